// Round 7
// baseline (194.504 us; speedup 1.0000x reference)
//
#include <hip/hip_runtime.h>

typedef unsigned short u16;
typedef unsigned int u32;
// may_alias: reinterpret-cast LDS/global vector access (prevent TBAA reorder).
typedef __attribute__((ext_vector_type(8), may_alias)) short short8;
typedef __attribute__((ext_vector_type(4), may_alias)) u32 uint4_ma;
typedef __attribute__((ext_vector_type(2), may_alias)) u32 uint2_ma;
typedef __attribute__((ext_vector_type(4), may_alias)) float floatx4_ma;
typedef __attribute__((ext_vector_type(4))) float floatx4;

#define DEV static __device__ __forceinline__

constexpr int S = 128, NRES = 256, D = 256, H = 8;
constexpr int M = S * NRES;                        // 32768 rows
constexpr float ATT_SCALE = 0.17677669529663687f;  // 1/sqrt(32)

DEV float bf2f(u16 h) {
  union { u32 u; float f; } v; v.u = ((u32)h) << 16; return v.f;
}
DEV u16 f2bf(float f) {
  union { float f; u32 u; } v; v.f = f;
  u32 u = v.u;
  return (u16)((u + 0x7fffu + ((u >> 16) & 1u)) >> 16);  // RNE
}

// ---------------------------------------------------------------- LayerNorm
// f32 in (d_in), bf16 out (ws). One wave per row of 256; float4/lane.
__global__ __launch_bounds__(256) void ln_kernel(const float* __restrict__ x,
                                                 const float* __restrict__ w,
                                                 const float* __restrict__ b,
                                                 u16* __restrict__ xn) {
  const int lane = threadIdx.x & 63;
  const int row = blockIdx.x * 4 + (threadIdx.x >> 6);
  floatx4_ma d = ((const floatx4_ma*)(x + (size_t)row * D))[lane];
  float s = d[0] + d[1] + d[2] + d[3];
  float ss = d[0] * d[0] + d[1] * d[1] + d[2] * d[2] + d[3] * d[3];
#pragma unroll
  for (int off = 32; off > 0; off >>= 1) {
    s += __shfl_xor(s, off, 64);
    ss += __shfl_xor(ss, off, 64);
  }
  const float mean = s * (1.0f / D);
  const float var = ss * (1.0f / D) - mean * mean;
  const float rstd = rsqrtf(var + 1e-5f);
  floatx4_ma wd = ((const floatx4_ma*)w)[lane];
  floatx4_ma bd = ((const floatx4_ma*)b)[lane];
  uint2_ma o;
  o.x = (u32)f2bf((d[0] - mean) * rstd * wd[0] + bd[0]) |
        ((u32)f2bf((d[1] - mean) * rstd * wd[1] + bd[1]) << 16);
  o.y = (u32)f2bf((d[2] - mean) * rstd * wd[2] + bd[2]) |
        ((u32)f2bf((d[3] - mean) * rstd * wd[3] + bd[3]) << 16);
  ((uint2_ma*)(xn + (size_t)row * D))[lane] = o;
}

// ------------------------------------------------------- staging helpers
// A (bf16) tile: async DMA, XOR-granule swizzle LDS[r][g]=global[r][g^(r&7)].
DEV void stage_A_async(const u16* Arows, u16* As, int lane, int wv) {
  const char* Ag = (const char*)Arows;
  const int gl = lane & 31;
  const int rofs = lane >> 5;
#pragma unroll
  for (int it = 0; it < 8; ++it) {
    const int idx = wv * 8 + it;
    const int r = idx * 2 + rofs;
    const int gofs = r * 512 + ((gl ^ (r & 7)) << 4);
    const int lofs = idx * 1024;
    __builtin_amdgcn_global_load_lds(
        (const __attribute__((address_space(1))) u32*)(Ag + gofs),
        (__attribute__((address_space(3))) u32*)((char*)As + lofs), 16, 0, 0);
  }
}
// W (f32) tile: vector load + convert to bf16 + swizzled ds_write_b128.
DEV void stage_W(const float* Wrows, u16* Bs, int tid) {
#pragma unroll
  for (int it = 0; it < 8; ++it) {
    const int gi = it * 256 + tid;
    const int r = gi >> 5;
    const int g = gi & 31;
    const float* src = Wrows + r * 256 + g * 8;
    floatx4_ma f0 = *(const floatx4_ma*)src;
    floatx4_ma f1 = *(const floatx4_ma*)(src + 4);
    short8 hv;
    hv[0] = (short)f2bf(f0[0]); hv[1] = (short)f2bf(f0[1]);
    hv[2] = (short)f2bf(f0[2]); hv[3] = (short)f2bf(f0[3]);
    hv[4] = (short)f2bf(f1[0]); hv[5] = (short)f2bf(f1[1]);
    hv[6] = (short)f2bf(f1[2]); hv[7] = (short)f2bf(f1[3]);
    *(short8*)(Bs + r * 256 + ((g ^ (r & 7)) << 3)) = hv;
  }
}
// Shared 64x64 MFMA core: acc[i][j] over K=256 from swizzled As/Bs.
DEV void mfma_core(const u16* As, const u16* Bs, int lane, int wv, floatx4 acc[2][2]) {
  const int wr = wv >> 1, wc = wv & 1;
  const int q4 = lane >> 4, r16 = lane & 15;
#pragma unroll
  for (int kk = 0; kk < 8; ++kk) {
    const int G = kk * 4 + q4;
    short8 a[2], b[2];
#pragma unroll
    for (int i = 0; i < 2; ++i) {
      const int mr = wr * 32 + i * 16 + r16;
      a[i] = *(const short8*)(As + mr * 256 + ((G ^ (mr & 7)) << 3));
      const int nr = wc * 32 + i * 16 + r16;
      b[i] = *(const short8*)(Bs + nr * 256 + ((G ^ (nr & 7)) << 3));
    }
#pragma unroll
    for (int i = 0; i < 2; ++i)
#pragma unroll
      for (int j = 0; j < 2; ++j)
        acc[i][j] = __builtin_amdgcn_mfma_f32_16x16x32_bf16(a[i], b[j], acc[i][j], 0, 0, 0);
  }
}

// ------------------------------------------------------------ QKV GEMM
// C[m][n] = sum_k A[m][k] * W[n][k]. A bf16 (ws), W f32 (d_in), C bf16 (ws).
__global__ __launch_bounds__(256) void gemm_qkv_kernel(
    const u16* __restrict__ A,
    const float* __restrict__ W0, const float* __restrict__ W1, const float* __restrict__ W2,
    u16* __restrict__ C0, u16* __restrict__ C1, u16* __restrict__ C2) {
  alignas(16) __shared__ u16 As[64 * 256];
  alignas(16) __shared__ u16 Bs[64 * 256];
  const int tid = threadIdx.x;
  const int lane = tid & 63;
  const int wv = tid >> 6;
  const int m0 = blockIdx.x * 64;
  const int n0 = blockIdx.y * 64;
  const float* Wp = (blockIdx.z == 0) ? W0 : ((blockIdx.z == 1) ? W1 : W2);
  u16* Cp = (blockIdx.z == 0) ? C0 : ((blockIdx.z == 1) ? C1 : C2);

  stage_A_async(A + (size_t)m0 * 256, As, lane, wv);
  stage_W(Wp + (size_t)n0 * 256, Bs, tid);
  __syncthreads();

  floatx4 acc[2][2] = {};
  mfma_core(As, Bs, lane, wv, acc);

  const int wr = wv >> 1, wc = wv & 1;
  const int q4 = lane >> 4, r16 = lane & 15;
#pragma unroll
  for (int j = 0; j < 2; ++j) {
    const int col = n0 + wc * 32 + j * 16 + r16;
#pragma unroll
    for (int i = 0; i < 2; ++i) {
      const int mbase = m0 + wr * 32 + i * 16 + q4 * 4;
#pragma unroll
      for (int r = 0; r < 4; ++r)
        Cp[(size_t)(mbase + r) * 256 + col] = f2bf(acc[i][j][r]);
    }
  }
}

// ------------------------------------------------------------ out-proj GEMM
// OUT[m][n] = sum_k AO[m][k] * WO[n][k] + bo[n]. AO bf16 (ws), WO/bo f32,
// OUT FLOAT32 (d_out) -- the round-7 fix.
__global__ __launch_bounds__(256) void gemm_out_kernel(
    const u16* __restrict__ AO, const float* __restrict__ WO,
    const float* __restrict__ bo, float* __restrict__ OUT) {
  alignas(16) __shared__ u16 As[64 * 256];
  alignas(16) __shared__ u16 Bs[64 * 256];
  const int tid = threadIdx.x;
  const int lane = tid & 63;
  const int wv = tid >> 6;
  const int m0 = blockIdx.x * 64;
  const int n0 = blockIdx.y * 64;

  stage_A_async(AO + (size_t)m0 * 256, As, lane, wv);
  stage_W(WO + (size_t)n0 * 256, Bs, tid);
  __syncthreads();

  floatx4 acc[2][2] = {};
  mfma_core(As, Bs, lane, wv, acc);

  const int wr = wv >> 1, wc = wv & 1;
  const int q4 = lane >> 4, r16 = lane & 15;
#pragma unroll
  for (int j = 0; j < 2; ++j) {
    const int col = n0 + wc * 32 + j * 16 + r16;
    const float bv = bo[col];
#pragma unroll
    for (int i = 0; i < 2; ++i) {
      const int mbase = m0 + wr * 32 + i * 16 + q4 * 4;
#pragma unroll
      for (int r = 0; r < 4; ++r)
        OUT[(size_t)(mbase + r) * 256 + col] = acc[i][j][r] + bv;
    }
  }
}

// ------------------------------------------------------------ row attention
// one block per (h, s_local). Q/K/V/O are ws bf16. K + V^T staged to LDS,
// register softmax (16-lane shuffles), P via per-wave swizzled LDS.
__global__ __launch_bounds__(256) void attn_kernel(
    const u16* __restrict__ Q, const u16* __restrict__ K, const u16* __restrict__ V,
    u16* __restrict__ O) {
  alignas(16) __shared__ u16 Ksh[256 * 32];      // [kj][d]
  alignas(16) __shared__ u16 Vt[32 * 264];       // [d][kj], +8 pad
  alignas(16) __shared__ u16 Psh[4][16 * 256];   // per-wave P, swizzled
  const int h = blockIdx.x;
  const int s = blockIdx.y;
  const int tid = threadIdx.x;
  const int lane = tid & 63;
  const int wv = tid >> 6;
  const int q4 = lane >> 4, r16 = lane & 15;
  const size_t rowbase = (size_t)s * 256;

  {  // stage K and V (transposed)
    const int r4 = tid >> 2;
    const int ch = tid & 3;
#pragma unroll
    for (int p = 0; p < 4; ++p) {
      const int row = p * 64 + r4;
      const size_t gofs = (rowbase + row) * 256 + h * 32 + ch * 8;
      *(uint4_ma*)(Ksh + row * 32 + ch * 8) = *(const uint4_ma*)(K + gofs);
      uint4_ma vvl = *(const uint4_ma*)(V + gofs);
      const u16* ve = (const u16*)&vvl;
#pragma unroll
      for (int e = 0; e < 8; ++e)
        Vt[(ch * 8 + e) * 264 + row] = ve[e];
    }
  }
  __syncthreads();

  u16* P = Psh[wv];
#pragma unroll 1
  for (int mt0 = 0; mt0 < 4; ++mt0) {
    const int qbase = (mt0 * 4 + wv) * 16;
    const short8 aq = *(const short8*)(Q + (rowbase + qbase + r16) * 256 + h * 32 + q4 * 8);
    floatx4 sc[16];
#pragma unroll
    for (int t = 0; t < 16; ++t) {
      const short8 bk = *(const short8*)(Ksh + (t * 16 + r16) * 32 + q4 * 8);
      floatx4 z = {0.f, 0.f, 0.f, 0.f};
      sc[t] = __builtin_amdgcn_mfma_f32_16x16x32_bf16(aq, bk, z, 0, 0, 0);
    }
    float inv[4];
#pragma unroll
    for (int r = 0; r < 4; ++r) {
      float mx = sc[0][r];
#pragma unroll
      for (int t = 1; t < 16; ++t) mx = fmaxf(mx, sc[t][r]);
      mx = fmaxf(mx, __shfl_xor(mx, 1, 64));
      mx = fmaxf(mx, __shfl_xor(mx, 2, 64));
      mx = fmaxf(mx, __shfl_xor(mx, 4, 64));
      mx = fmaxf(mx, __shfl_xor(mx, 8, 64));
      float sum = 0.f;
#pragma unroll
      for (int t = 0; t < 16; ++t) {
        const float p = __expf((sc[t][r] - mx) * ATT_SCALE);
        sc[t][r] = p;
        sum += p;
      }
      sum += __shfl_xor(sum, 1, 64);
      sum += __shfl_xor(sum, 2, 64);
      sum += __shfl_xor(sum, 4, 64);
      sum += __shfl_xor(sum, 8, 64);
      inv[r] = 1.0f / sum;
    }
#pragma unroll
    for (int t = 0; t < 16; ++t) {
      const int col = t * 16 + r16;
      const int g = col >> 3, cb = col & 7;
#pragma unroll
      for (int r = 0; r < 4; ++r) {
        const int m_ = q4 * 4 + r;
        P[m_ * 256 + ((g ^ (m_ & 7)) << 3) + cb] = f2bf(sc[t][r]);
      }
    }
    __syncthreads();  // P writes -> P reads (lgkm drain + compiler fence)
    floatx4 o0 = {0.f, 0.f, 0.f, 0.f}, o1 = {0.f, 0.f, 0.f, 0.f};
#pragma unroll
    for (int kk = 0; kk < 8; ++kk) {
      const int G = kk * 4 + q4;
      const short8 ap = *(const short8*)(P + r16 * 256 + ((G ^ (r16 & 7)) << 3));
      const short8 bv0 = *(const short8*)(Vt + r16 * 264 + kk * 32 + q4 * 8);
      const short8 bv1 = *(const short8*)(Vt + (16 + r16) * 264 + kk * 32 + q4 * 8);
      o0 = __builtin_amdgcn_mfma_f32_16x16x32_bf16(ap, bv0, o0, 0, 0, 0);
      o1 = __builtin_amdgcn_mfma_f32_16x16x32_bf16(ap, bv1, o1, 0, 0, 0);
    }
#pragma unroll
    for (int r = 0; r < 4; ++r) {
      const size_t ob = (rowbase + qbase + q4 * 4 + r) * 256 + h * 32;
      O[ob + r16] = f2bf(o0[r] * inv[r]);
      O[ob + 16 + r16] = f2bf(o1[r] * inv[r]);
    }
    __syncthreads();  // P reads -> next iter's writes
  }
}

// ---------------------------------------------------------------- launch
extern "C" void kernel_launch(void* const* d_in, const int* in_sizes, int n_in,
                              void* d_out, int out_size, void* d_ws, size_t ws_size,
                              hipStream_t stream) {
  (void)in_sizes; (void)n_in; (void)out_size;
  // All inputs FLOAT32 (reference dtypes); output FLOAT32.
  const float* msa = (const float*)d_in[0];
  const float* lnw = (const float*)d_in[1];
  const float* lnb = (const float*)d_in[2];
  const float* wq = (const float*)d_in[3];
  const float* wk = (const float*)d_in[4];
  const float* wvp = (const float*)d_in[5];
  const float* wo = (const float*)d_in[6];
  const float* bo = (const float*)d_in[7];
  float* out = (float*)d_out;

  // Per-chunk scratch in ws: xn, q, k, v (bf16), ao aliases xn.
  // Need CS * 4 * 256*256 * 2 B = CS * 512 KiB.
  int CS = S;  // s-rows per chunk, pow2
  while (CS > 1 && (size_t)CS * 524288ull > ws_size) CS >>= 1;
  const int nch = S / CS;
  const size_t chunkElems = (size_t)CS * NRES * D;  // per tensor
  u16* xnc = (u16*)d_ws;
  u16* qc = xnc + chunkElems;
  u16* kc = qc + chunkElems;
  u16* vc = kc + chunkElems;
  u16* aoc = xnc;  // xn dead after QKV GEMM

  const int mrows = CS * NRES;  // rows per chunk
  for (int c = 0; c < nch; ++c) {
    const size_t row0 = (size_t)c * mrows;
    ln_kernel<<<mrows / 4, 256, 0, stream>>>(msa + row0 * D, lnw, lnb, xnc);
    gemm_qkv_kernel<<<dim3(mrows / 64, 4, 3), 256, 0, stream>>>(xnc, wq, wk, wvp, qc, kc, vc);
    attn_kernel<<<dim3(H, CS), 256, 0, stream>>>(qc, kc, vc, aoc);
    gemm_out_kernel<<<dim3(mrows / 64, 4), 256, 0, stream>>>(aoc, wo, bo, out + row0 * D);
  }
}